// Round 1
// baseline (117.419 us; speedup 1.0000x reference)
//
#include <hip/hip_runtime.h>

#define NN 192
#define BZ 4
#define YC 12
#define NTHR (64 * BZ)
#define GX (NN / YC)      // 16 y-chunks
#define GZ (NN / BZ)      // 48 z-chunks
#define NBLK (GX * GZ)    // 768 blocks = exactly 3 per CU

// x is mapped across the 64 lanes of a wave, 3 floats per lane:
// lane l owns x = 3l .. 3l+2; a whole wave = one full x-row (192).
// The x-halo (x-1 / x+3) comes from neighbor lanes via shuffle.

// One row: given the lane's 3 values, produce
//   a[i] = w[x+1] - w[x-1]   (x-diff)
//   b[i] = w[x-1]+w[x]+w[x+1] (x-box), i = 0..2, with edge clamp at x=0/191.
__device__ __forceinline__ void row_ab(float c0, float c1, float c2, int lane,
                                       float a[3], float b[3]) {
    float L = __shfl_up(c2, 1, 64);    // neighbor lane-1's last element = x-1
    float R = __shfl_down(c0, 1, 64);  // neighbor lane+1's first element = x+3
    if (lane == 0)  L = c0;            // clamp x=-1 -> 0
    if (lane == 63) R = c2;            // clamp x=192 -> 191
    a[0] = c1 - L;
    a[1] = c2 - c0;
    a[2] = R - c1;
    b[0] = L + c0 + c1;
    b[1] = c0 + c1 + c2;
    b[2] = c1 + c2 + R;
}

// Fold one y-plane of one array (rows at z-1,z,z+1) into slot quantities:
//   sa = sum_dz a   (-> Ix),  sb = sum_dz b  (-> Iy),  tb = b(z+1)-b(z-1) (-> Iz)
__device__ __forceinline__ void fold_plane(const float3 r[3], int lane,
                                           float sa[3], float sb[3], float tb[3]) {
    float am[3], bm[3], a0[3], b0[3], ap[3], bp[3];
    row_ab(r[0].x, r[0].y, r[0].z, lane, am, bm);
    row_ab(r[1].x, r[1].y, r[1].z, lane, a0, b0);
    row_ab(r[2].x, r[2].y, r[2].z, lane, ap, bp);
#pragma unroll
    for (int i = 0; i < 3; ++i) {
        sa[i] = am[i] + a0[i] + ap[i];
        sb[i] = bm[i] + b0[i] + bp[i];
        tb[i] = bp[i] - bm[i];
    }
}

__device__ __forceinline__ void load_plane(const float* const base[6], int yrow,
                                           float3 rI[3], float3 rJ[3]) {
#pragma unroll
    for (int d = 0; d < 3; ++d) rI[d] = *reinterpret_cast<const float3*>(base[d] + yrow);
#pragma unroll
    for (int d = 0; d < 3; ++d) rJ[d] = *reinterpret_cast<const float3*>(base[3 + d] + yrow);
}

// Raw (un-halved) gradients: rawG = 2*trueG; the 0.5^2 factors cancel in ngf
// when EPS^2 (0.01) is replaced by 4*EPS^2 = 0.04.
__global__ __launch_bounds__(NTHR, 2) void ngf_kernel(const float* __restrict__ I,
                                                      const float* __restrict__ J,
                                                      const float* __restrict__ M,
                                                      float* __restrict__ out) {
    const int lane = threadIdx.x;         // 0..63
    const int tz = threadIdx.y;
    const int xoff = lane * 3;

    // XCD-grouped bijective swizzle: dispatch order round-robins XCDs, so
    // original flat ids congruent mod 8 land on one XCD. Remap so each XCD
    // owns a contiguous chunk of 96 blocks = a contiguous z-span (6 z-chunks),
    // making shared z-halo planes L2-temporal hits. Bijective since 768%8==0.
    const int flat0 = blockIdx.y * GX + blockIdx.x;
    const int flat  = (flat0 & 7) * (NBLK / 8) + (flat0 >> 3);
    const int ybase = (flat % GX) * YC;
    const int z     = (flat / GX) * BZ + tz;

    const int gzm = (z == 0) ? 0 : z - 1;
    const int gzp = (z == NN - 1) ? (NN - 1) : z + 1;

    const float* base[6] = {
        I + gzm * NN * NN + xoff, I + z * NN * NN + xoff, I + gzp * NN * NN + xoff,
        J + gzm * NN * NN + xoff, J + z * NN * NN + xoff, J + gzp * NN * NN + xoff};
    const float* mbase = M + z * NN * NN + xoff;

    float sa[2][3][3], sb[2][3][3], tb[2][3][3];

    // ---- seed: fold plane y=ybase-1 (clamped) into slot 0, y=ybase into slot 1
    {
        float3 rI[3], rJ[3];
        load_plane(base, ((ybase == 0) ? 0 : (ybase - 1)) * NN, rI, rJ);
        fold_plane(rI, lane, sa[0][0], sb[0][0], tb[0][0]);
        fold_plane(rJ, lane, sa[1][0], sb[1][0], tb[1][0]);
        load_plane(base, ybase * NN, rI, rJ);
        fold_plane(rI, lane, sa[0][1], sb[0][1], tb[0][1]);
        fold_plane(rJ, lane, sa[1][1], sb[1][1], tb[1][1]);
    }

    // raw-plane double buffer (18+18 floats) + mask; prefetch plane ybase+1
    float3 bI[2][3], bJ[2][3];
    load_plane(base, (ybase + 1) * NN, bI[0], bJ[0]);   // ybase+1 <= 181
    float3 mcur = *reinterpret_cast<const float3*>(mbase + ybase * NN);

    float acc = 0.0f;
#pragma unroll
    for (int yy = 0; yy < YC; ++yy) {
        const int cb = yy & 1, nb = cb ^ 1;   // constant after unroll

        // 1) issue next plane's 7 loads (consumed next iteration)
        float3 mnxt = mcur;
        if (yy < YC - 1) {
            int gy = ybase + yy + 2;
            gy = (gy > NN - 1) ? (NN - 1) : gy;
            load_plane(base, gy * NN, bI[nb], bJ[nb]);
            mnxt = *reinterpret_cast<const float3*>(mbase + (ybase + yy + 1) * NN);
        }

        // 2) fold plane y = ybase+yy+1 (its loads were issued one step ago)
        const int sC = (yy + 2) % 3;
        fold_plane(bI[cb], lane, sa[0][sC], sb[0][sC], tb[0][sC]);
        fold_plane(bJ[cb], lane, sa[1][sC], sb[1][sC], tb[1][sC]);

        // 3) NGF at y = ybase+yy (slots yy, yy+1, yy+2 live)
        const int s0 = yy % 3, s1 = (yy + 1) % 3;
        const float mm[3] = {mcur.x, mcur.y, mcur.z};
#pragma unroll
        for (int i = 0; i < 3; ++i) {
            const float Ix = sa[0][s0][i] + sa[0][s1][i] + sa[0][sC][i];
            const float Iy = sb[0][sC][i] - sb[0][s0][i];
            const float Iz = tb[0][s0][i] + tb[0][s1][i] + tb[0][sC][i];
            const float Jx = sa[1][s0][i] + sa[1][s1][i] + sa[1][sC][i];
            const float Jy = sb[1][sC][i] - sb[1][s0][i];
            const float Jz = tb[1][s0][i] + tb[1][s1][i] + tb[1][sC][i];
            const float im = Ix * Ix + Iy * Iy + Iz * Iz + 0.04f;
            const float jm = Jx * Jx + Jy * Jy + Jz * Jz + 0.04f;
            const float dot = Ix * Jx + Iy * Jy + Iz * Jz;
            acc += (1.0f - dot * dot * __builtin_amdgcn_rcpf(im * jm)) * mm[i];
        }
        mcur = mnxt;
    }

    // mean scaling, then wave -> block -> global reduction
    acc *= (1.0f / ((float)NN * (float)NN * (float)NN));
#pragma unroll
    for (int off = 32; off > 0; off >>= 1)
        acc += __shfl_down(acc, off, 64);

    __shared__ float red[NTHR / 64];
    const int flatt = tz * 64 + lane;
    if ((flatt & 63) == 0) red[flatt >> 6] = acc;
    __syncthreads();
    if (flatt == 0) {
        float s = 0.0f;
#pragma unroll
        for (int w = 0; w < NTHR / 64; ++w) s += red[w];
        atomicAdd(out, s);
    }
}

extern "C" void kernel_launch(void* const* d_in, const int* in_sizes, int n_in,
                              void* d_out, int out_size, void* d_ws, size_t ws_size,
                              hipStream_t stream) {
    const float* I = (const float*)d_in[0];
    const float* J = (const float*)d_in[1];
    const float* M = (const float*)d_in[2];
    float* out = (float*)d_out;

    hipMemsetAsync(d_out, 0, sizeof(float), stream);

    dim3 block(64, BZ);               // 256 threads = 4 waves
    dim3 grid(GX, GZ);                // (16, 48) = 768 blocks = 3/CU exact
    ngf_kernel<<<grid, block, 0, stream>>>(I, J, M, out);
}